// Round 5
// baseline (127.963 us; speedup 1.0000x reference)
//
#include <hip/hip_runtime.h>

typedef __attribute__((ext_vector_type(8))) short short8;
typedef __attribute__((ext_vector_type(4))) float float4v;
typedef __attribute__((ext_vector_type(4))) unsigned short us4;
typedef __attribute__((ext_vector_type(4))) unsigned int uint4v;

namespace {
constexpr int NG   = 16;
constexpr int LSEQ = 4096;
constexpr int CIN  = 1024;
constexpr int IPG  = 64;
constexpr int OPG  = 64;
constexpr int KT   = 5;
constexpr int ROWS = 128;                 // rows per block
constexpr int SIN_SLOTS  = 132 * 16;      // 16B slots (132 rows x 16)
constexpr int KSTEPS = 10;                // 320 K / 32
constexpr size_t WFRAG_SHORTS = (size_t)NG * 4 * KSTEPS * 512;  // 327,680
constexpr size_t WFRAG_BYTES  = WFRAG_SHORTS * 2;               // 655,360
constexpr size_t MASK_BYTES   = (size_t)4 * LSEQ;               // 16,384
}

__device__ __forceinline__ unsigned short f2bf(float f) {
  unsigned int u = __builtin_bit_cast(unsigned int, f);
  u += 0x7fffu + ((u >> 16) & 1u);   // RNE (inputs finite)
  return (unsigned short)(u >> 16);
}

// ---------------- fused prep: W-frag repack (blocks 0..159) + masks (160..223)
__global__ __launch_bounds__(256) void prep_fused(const float* __restrict__ gwt,
                                                  const int* __restrict__ gpos,
                                                  unsigned short* __restrict__ wfrag,
                                                  unsigned char* __restrict__ gmask) {
  if (blockIdx.x < 160) {
    const int u = blockIdx.x * 256 + threadIdx.x;           // 40960 threads
    const int E    = u * 8;
    const int tile = E >> 9;
    const int w9   = E & 511;
    const int n    = w9 >> 5;
    const int quad = (w9 & 31) >> 3;
    const int ks   = tile % KSTEPS;
    const int tt   = tile / KSTEPS;
    const int t    = tt & 3;
    const int g    = tt >> 2;
    const int tap  = ks >> 1;
    const int h    = ks & 1;
    const int o    = t * 16 + n;
    const float* src = gwt + (((size_t)(g * 64 + o) * 64) + h * 32 + quad * 8) * KT + tap;
    short8 v;
    #pragma unroll
    for (int j = 0; j < 8; ++j)
      v[j] = (short)f2bf(src[j * KT]);
    *(short8*)(wfrag + E) = v;
  } else {
    const int id = (blockIdx.x - 160) * 256 + threadIdx.x;  // 16384 threads
    const int b  = id >> 12;
    const int l  = id & (LSEQ - 1);
    const int base = b * LSEQ;
    const int pc = gpos[base + l];
    unsigned int mbits = 0;
    #pragma unroll
    for (int tap = 0; tap < KT; ++tap) {
      const int lsrc = l + tap - 2;
      int ok = 0;
      if (lsrc >= 0 && lsrc < LSEQ)
        ok = (gpos[base + lsrc] == pc + (tap - 2));
      mbits |= (unsigned int)ok << tap;
    }
    gmask[id] = (unsigned char)mbits;
  }
}

// ---------------- main v6: DMA staging + full-drain __syncthreads (SAFE) -----
// R4's counted vmcnt(8) raced across graph replays (compiler-emitted vmem count
// is not source-controllable -> m152 lesson). This version keeps the three
// uninvalidated wins -- global_load_lds DMA staging (no RA battle, R2/R3 fix),
// fp32-in-LDS with v_cvt_pk_bf16_f32 at read, both-sides XOR swizzle for
// conflict-free ds_read_b128 -- under a single conservative __syncthreads()
// (vmcnt(0)+lgkmcnt(0) drain). Latency hiding is pure TLP: 33.8 KB LDS ->
// 4 blocks/CU, 16 waves/CU; one block's drain overlaps neighbors' compute.
__global__ __launch_bounds__(256) void mconv_main6(
    const float* __restrict__ gin,            // (4,4096,1024) fp32
    const unsigned char* __restrict__ gmask,  // (4,4096) mask bytes
    const unsigned short* __restrict__ wfrag, // bf16 frag buffer
    float* __restrict__ gout) {               // (4,4096,16,64) fp32
  __shared__ __align__(16) float sIn[SIN_SLOTS * 4];   // 33,792 B

  const int tid  = threadIdx.x;
  const int wv   = tid >> 6;
  const int lane = tid & 63;
  const int quad = lane >> 4;
  const int l16  = lane & 15;
  const int wm   = wv & 1;        // M half: rows [wm*64, wm*64+64)
  const int wn   = wv >> 1;       // N half: cols [wn*32, wn*32+32)

  const int g  = blockIdx.y;
  const int b  = blockIdx.z;
  const int l0 = blockIdx.x * ROWS;
  const int bL = b * LSEQ;

  const float* ginb = gin + (size_t)bL * CIN + g * IPG;

  // ---- one 16B DMA: physical slot u -> (row r, phys slot ps); logical col
  //      c4 = ps ^ (r&7). Swizzle applied on the GLOBAL SOURCE address; LDS
  //      dest is linear base+lane*16 (global_load_lds requirement, rule #21).
  auto stage_one = [&](int u) {
    const int r  = u >> 4;
    const int ps = u & 15;
    const int c4 = ps ^ (r & 7);
    int l = l0 - 2 + r;
    l = l < 0 ? 0 : (l > LSEQ - 1 ? LSEQ - 1 : l);   // clamped rows masked at use
    const float* src = ginb + (size_t)l * CIN + c4 * 4;
    __builtin_amdgcn_global_load_lds(
        (const __attribute__((address_space(1))) void*)(const void*)src,
        (__attribute__((address_space(3))) void*)(void*)&sIn[u * 4],
        16, 0, 0);
  };

  // ---- issue all 2112 slot DMAs (9 per thread; tail slots by wave 0)
  #pragma unroll
  for (int k = 0; k < 8; ++k)
    stage_one(tid + k * 256);
  if (wv == 0)
    stage_one(tid + 2048);          // slots 2048..2111

  // ---- masks (tiny L2-hot loads; drained by the same syncthreads)
  int mb[4];
  #pragma unroll
  for (int mt = 0; mt < 4; ++mt)
    mb[mt] = gmask[bL + l0 + wm * 64 + mt * 16 + l16];

  // ---- B-frag bases (register prefetch depth 1)
  const int laneoff = l16 * 32 + quad * 8;
  const unsigned short* wb0 = wfrag + (size_t)((g * 4 + wn * 2) * KSTEPS) * 512 + laneoff;
  const unsigned short* wb1 = wb0 + (size_t)KSTEPS * 512;
  const short8 zero8 = {0, 0, 0, 0, 0, 0, 0, 0};
  const float4v zf = {0.f, 0.f, 0.f, 0.f};

  __syncthreads();   // conservative drain: vmcnt(0) lgkmcnt(0) + s_barrier

  float4v acc[4][2];
  #pragma unroll
  for (int mt = 0; mt < 4; ++mt) { acc[mt][0] = zf; acc[mt][1] = zf; }
  short8 bc0 = *(const short8*)(wb0);
  short8 bc1 = *(const short8*)(wb1);

  #pragma unroll 2
  for (int ks = 0; ks < KSTEPS; ++ks) {
    const int ksn = (ks + 1 < KSTEPS) ? ks + 1 : KSTEPS - 1;
    short8 bn0 = *(const short8*)(wb0 + ksn * 512);
    short8 bn1 = *(const short8*)(wb1 + ksn * 512);
    const int tap = ks >> 1;
    const int h   = ks & 1;
    const int ls  = h * 8 + quad * 2;                 // even logical 16B slot
    #pragma unroll
    for (int mt = 0; mt < 4; ++mt) {
      const int r   = wm * 64 + mt * 16 + l16 + tap;  // LDS row (halo-offset)
      const int swz = r & 7;
      const float* rowp = &sIn[r * 64];
      float4v lo = *(const float4v*)(rowp + ((ls ^ swz) << 2));
      float4v hi = *(const float4v*)(rowp + (((ls + 1) ^ swz) << 2));
      unsigned int d0, d1, d2, d3;
      asm("v_cvt_pk_bf16_f32 %0, %1, %2" : "=v"(d0) : "v"(lo[0]), "v"(lo[1]));
      asm("v_cvt_pk_bf16_f32 %0, %1, %2" : "=v"(d1) : "v"(lo[2]), "v"(lo[3]));
      asm("v_cvt_pk_bf16_f32 %0, %1, %2" : "=v"(d2) : "v"(hi[0]), "v"(hi[1]));
      asm("v_cvt_pk_bf16_f32 %0, %1, %2" : "=v"(d3) : "v"(hi[2]), "v"(hi[3]));
      uint4v dv = {d0, d1, d2, d3};
      short8 a = __builtin_bit_cast(short8, dv);
      if (!((mb[mt] >> tap) & 1)) a = zero8;
      acc[mt][0] = __builtin_amdgcn_mfma_f32_16x16x32_bf16(a, bc0, acc[mt][0], 0, 0, 0);
      acc[mt][1] = __builtin_amdgcn_mfma_f32_16x16x32_bf16(a, bc1, acc[mt][1], 0, 0, 0);
    }
    bc0 = bn0; bc1 = bn1;
  }

  // ---- epilogue: C/D layout col=l16, row=quad*4+reg
  #pragma unroll
  for (int mt = 0; mt < 4; ++mt) {
    const int lrow = l0 + wm * 64 + mt * 16 + quad * 4;
    #pragma unroll
    for (int reg = 0; reg < 4; ++reg) {
      float* orow = gout + (size_t)(bL + lrow + reg) * CIN + g * OPG + wn * 32;
      orow[l16]      = acc[mt][0][reg];
      orow[16 + l16] = acc[mt][1][reg];
    }
  }
}

// ---------------- fallback (known-good R3 kernel, used if ws too small) -----
namespace fb {
constexpr int ROWS_PER_CHUNK = 128;
constexpr int CHUNKS = 4;
constexpr int ROWS_PER_BLOCK = 512;
constexpr int SW_STRIDE  = 328;
constexpr int FSIN_STRIDE = 72;
constexpr int FSIN_ROWS   = 132;
}

__global__ __launch_bounds__(256, 2) void mconv_f32_mfma(
    const float* __restrict__ gin, const int* __restrict__ gpos,
    const float* __restrict__ gwt, float* __restrict__ gout) {
  using namespace fb;
  __shared__ __align__(16) unsigned short sW[OPG * SW_STRIDE];
  __shared__ __align__(16) unsigned short sIn[FSIN_ROWS * FSIN_STRIDE];
  __shared__ unsigned char sMask[ROWS_PER_CHUNK * KT];

  const int tid  = threadIdx.x;
  const int wave = tid >> 6;
  const int lane = tid & 63;
  const int quad = lane >> 4;
  const int l16  = lane & 15;
  const int g  = blockIdx.y;
  const int b  = blockIdx.z;
  const int tile0 = blockIdx.x * ROWS_PER_BLOCK;
  const int bL = b * LSEQ;

  {
    const float* wg = gwt + (size_t)g * (OPG * IPG * KT);
    for (int u = tid; u < (OPG * IPG * KT) / 4; u += 256) {
      const int base = u * 4;
      float4v v = *(const float4v*)(wg + base);
      int o = base / (IPG * KT);
      int r = base - o * (IPG * KT);
      int i = r / KT;
      int k = r - i * KT;
      int addr = o * SW_STRIDE + k * IPG + i;
      #pragma unroll
      for (int t = 0; t < 4; ++t) {
        sW[addr] = f2bf(v[t]);
        ++k; addr += IPG;
        if (k == KT) { k = 0; ++i; addr -= KT * IPG - 1; }
      }
    }
  }
  const short8 zero8 = {0,0,0,0,0,0,0,0};
  const float4v zf = {0.f,0.f,0.f,0.f};
  for (int ch = 0; ch < CHUNKS; ++ch) {
    const int l0 = tile0 + ch * ROWS_PER_CHUNK;
    __syncthreads();
    for (int t = tid; t < ROWS_PER_CHUNK * KT; t += 256) {
      const int lr = t / KT, tap = t - lr * KT, l = l0 + lr, lsrc = l + tap - 2;
      int ok = 0;
      if (lsrc >= 0 && lsrc < LSEQ) ok = (gpos[bL + lsrc] == gpos[bL + l] + (tap - 2));
      sMask[t] = (unsigned char)ok;
    }
    for (int u = tid; u < FSIN_ROWS * 16; u += 256) {
      const int r = u >> 4, c4 = u & 15, l = l0 - 2 + r;
      us4 w = {0,0,0,0};
      if (l >= 0 && l < LSEQ) {
        float4v v = *(const float4v*)(gin + (size_t)(bL + l) * CIN + g * IPG + c4 * 4);
        w[0]=f2bf(v[0]); w[1]=f2bf(v[1]); w[2]=f2bf(v[2]); w[3]=f2bf(v[3]);
      }
      *(us4*)(&sIn[r * FSIN_STRIDE + c4 * 4]) = w;
    }
    __syncthreads();
    float4v acc[2][4];
    #pragma unroll
    for (int mm = 0; mm < 2; ++mm)
      #pragma unroll
      for (int nt = 0; nt < 4; ++nt) acc[mm][nt] = zf;
    const int m0 = wave * 32 + l16, m1 = m0 + 16;
    #pragma unroll
    for (int tap = 0; tap < KT; ++tap) {
      const bool msk0 = sMask[m0 * KT + tap] != 0;
      const bool msk1 = sMask[m1 * KT + tap] != 0;
      #pragma unroll
      for (int h = 0; h < 2; ++h) {
        const int kk = tap * IPG + h * 32 + quad * 8;
        const short8 b0 = *(const short8*)(&sW[(0*16 + l16) * SW_STRIDE + kk]);
        const short8 b1 = *(const short8*)(&sW[(1*16 + l16) * SW_STRIDE + kk]);
        const short8 b2 = *(const short8*)(&sW[(2*16 + l16) * SW_STRIDE + kk]);
        const short8 b3 = *(const short8*)(&sW[(3*16 + l16) * SW_STRIDE + kk]);
        const int ci = h * 32 + quad * 8;
        short8 a0 = *(const short8*)(&sIn[(m0 + tap) * FSIN_STRIDE + ci]);
        short8 a1 = *(const short8*)(&sIn[(m1 + tap) * FSIN_STRIDE + ci]);
        if (!msk0) a0 = zero8;
        if (!msk1) a1 = zero8;
        acc[0][0] = __builtin_amdgcn_mfma_f32_16x16x32_bf16(a0,b0,acc[0][0],0,0,0);
        acc[0][1] = __builtin_amdgcn_mfma_f32_16x16x32_bf16(a0,b1,acc[0][1],0,0,0);
        acc[0][2] = __builtin_amdgcn_mfma_f32_16x16x32_bf16(a0,b2,acc[0][2],0,0,0);
        acc[0][3] = __builtin_amdgcn_mfma_f32_16x16x32_bf16(a0,b3,acc[0][3],0,0,0);
        acc[1][0] = __builtin_amdgcn_mfma_f32_16x16x32_bf16(a1,b0,acc[1][0],0,0,0);
        acc[1][1] = __builtin_amdgcn_mfma_f32_16x16x32_bf16(a1,b1,acc[1][1],0,0,0);
        acc[1][2] = __builtin_amdgcn_mfma_f32_16x16x32_bf16(a1,b2,acc[1][2],0,0,0);
        acc[1][3] = __builtin_amdgcn_mfma_f32_16x16x32_bf16(a1,b3,acc[1][3],0,0,0);
      }
    }
    #pragma unroll
    for (int mm = 0; mm < 2; ++mm) {
      const int lrow = l0 + wave * 32 + mm * 16 + quad * 4;
      #pragma unroll
      for (int reg = 0; reg < 4; ++reg) {
        float* orow = gout + ((size_t)(bL + lrow + reg) * NG + g) * OPG;
        #pragma unroll
        for (int nt = 0; nt < 4; ++nt)
          orow[nt * 16 + l16] = acc[mm][nt][reg];
      }
    }
  }
}

extern "C" void kernel_launch(void* const* d_in, const int* in_sizes, int n_in,
                              void* d_out, int out_size, void* d_ws, size_t ws_size,
                              hipStream_t stream) {
  (void)in_sizes; (void)n_in; (void)out_size;
  const float* gin  = (const float*)d_in[0];
  const int*   gpos = (const int*)d_in[1];
  const float* gwt  = (const float*)d_in[2];
  float*       gout = (float*)d_out;

  if (ws_size >= WFRAG_BYTES + MASK_BYTES) {
    unsigned short* wfrag = (unsigned short*)d_ws;
    unsigned char*  gmask = (unsigned char*)d_ws + WFRAG_BYTES;
    hipLaunchKernelGGL(prep_fused, dim3(224), dim3(256), 0, stream,
                       gwt, gpos, wfrag, gmask);
    dim3 grid(LSEQ / ROWS, NG, 4);   // 32 x 16 x 4 = 2048 blocks
    hipLaunchKernelGGL(mconv_main6, grid, dim3(256), 0, stream,
                       gin, gmask, wfrag, gout);
  } else {
    dim3 grid(LSEQ / fb::ROWS_PER_BLOCK, NG, 4);
    hipLaunchKernelGGL(mconv_f32_mfma, grid, dim3(256), 0, stream,
                       gin, gpos, gwt, gout);
  }
}